// Round 2
// baseline (1125.582 us; speedup 1.0000x reference)
//
#include <hip/hip_runtime.h>
#include <stdint.h>

#define T_TOK 8192
#define HID   1024
#define FF    4096
#define NE    8
#define BM    128
#define BN    128
#define BK    64
#define CAP   (T_TOK*2 + NE*BM)          // 17408 slots max (padded)
#define MT_MAX ((T_TOK*2)/BM + NE)       // 136 m-tiles max

typedef __attribute__((ext_vector_type(4))) float f32x4;
typedef __attribute__((ext_vector_type(8))) short s16x8;

__device__ __forceinline__ unsigned short f2bf(float f) {
  unsigned u = __float_as_uint(f);
  u += 0x7FFF + ((u >> 16) & 1);         // round-to-nearest-even
  return (unsigned short)(u >> 16);
}

__device__ __forceinline__ void gload_lds16(const void* g, void* l) {
  __builtin_amdgcn_global_load_lds(
      (const __attribute__((address_space(1))) unsigned int*)g,
      (__attribute__((address_space(3))) unsigned int*)l, 16, 0, 0);
}

// ---------------- router: logits + top2 + softmax + counts ----------------
__global__ __launch_bounds__(256) void router_k(
    const float* __restrict__ x, const float* __restrict__ Wr,
    const float* __restrict__ br,
    int* __restrict__ top_i, float* __restrict__ top_w, int* __restrict__ counts)
{
  __shared__ float wlds[NE*HID];               // 32 KB
  int tid = threadIdx.x;
  for (int i = tid; i < NE*HID; i += 256) wlds[i] = Wr[i];
  __syncthreads();
  int wid = tid >> 6, lane = tid & 63;
  for (int t = blockIdx.x*4 + wid; t < T_TOK; t += gridDim.x*4) {
    const float* xr = x + (size_t)t*HID;
    float acc[NE];
#pragma unroll
    for (int e = 0; e < NE; ++e) acc[e] = 0.f;
    for (int i = lane; i < HID; i += 64) {
      float xv = xr[i];
#pragma unroll
      for (int e = 0; e < NE; ++e) acc[e] += xv * wlds[e*HID + i];
    }
#pragma unroll
    for (int e = 0; e < NE; ++e) {
      float v = acc[e];
#pragma unroll
      for (int o = 32; o > 0; o >>= 1) v += __shfl_down(v, o, 64);
      acc[e] = v;
    }
    if (lane == 0) {
      float v0 = -1e30f, v1 = -1e30f; int i0 = 0, i1 = 0;
#pragma unroll
      for (int e = 0; e < NE; ++e) {
        float v = acc[e] + br[e];
        if (v > v0)      { v1 = v0; i1 = i0; v0 = v; i0 = e; }
        else if (v > v1) { v1 = v;  i1 = e; }
      }
      float e1 = expf(v1 - v0);
      float w0 = 1.f / (1.f + e1);
      float w1 = e1 * w0;
      top_i[2*t] = i0;  top_i[2*t+1] = i1;
      top_w[2*t] = w0;  top_w[2*t+1] = w1;
      atomicAdd(&counts[i0], 1);
      atomicAdd(&counts[i1], 1);
    }
  }
}

// ---------------- plan: padded segments + m-tile tables ----------------
__global__ void plan_k(const int* __restrict__ counts, int* __restrict__ seg_start,
                       int* __restrict__ mtile_e, int* __restrict__ mtile_r0,
                       int* __restrict__ nmt)
{
  if (threadIdx.x == 0 && blockIdx.x == 0) {
    int acc = 0, mt = 0;
    for (int e = 0; e < NE; ++e) {
      seg_start[e] = acc;
      int c = counts[e];
      int tiles = (c + BM - 1) / BM;
      for (int i = 0; i < tiles; ++i) { mtile_e[mt] = e; mtile_r0[mt] = acc + i*BM; ++mt; }
      acc += tiles * BM;
    }
    nmt[0] = mt;
  }
}

__global__ void initslot_k(int* __restrict__ tok_of, float* __restrict__ w_of) {
  int i = blockIdx.x*256 + threadIdx.x;
  if (i < CAP) { tok_of[i] = 0; w_of[i] = 0.f; }
}

__global__ void scatter_k(const int* __restrict__ top_i, const float* __restrict__ top_w,
                          const int* __restrict__ seg_start, int* __restrict__ fill,
                          int* __restrict__ tok_of, float* __restrict__ w_of,
                          int* __restrict__ pair_slot)
{
  int t = blockIdx.x*256 + threadIdx.x;
  if (t >= T_TOK) return;
#pragma unroll
  for (int k = 0; k < 2; ++k) {
    int e = top_i[2*t+k];
    float w = top_w[2*t+k];
    int pos = atomicAdd(&fill[e], 1);
    int s = seg_start[e] + pos;
    tok_of[s] = t; w_of[s] = w; pair_slot[2*t+k] = s;
  }
}

// ---------------- fp32 -> bf16 conversion ----------------
__global__ void cvt_k(const float* __restrict__ src, unsigned short* __restrict__ dst, long n4)
{
  long i = (long)blockIdx.x*blockDim.x + threadIdx.x;
  long stride = (long)gridDim.x*blockDim.x;
  for (; i < n4; i += stride) {
    float4 v = ((const float4*)src)[i];
    ushort4 o;
    o.x = f2bf(v.x); o.y = f2bf(v.y); o.z = f2bf(v.z); o.w = f2bf(v.w);
    ((ushort4*)dst)[i] = o;
  }
}

// ---------------- GEMM1: Hbuf[slot][f] = gelu(X[tok]·W1[e]^T + b1) ----------------
__global__ __launch_bounds__(256, 2) void gemm1_k(
    const unsigned short* __restrict__ Xb,     // [T, H] bf16
    const unsigned short* __restrict__ W1b,    // [E, F, H] bf16
    const float* __restrict__ b1,              // [E, F]
    const int* __restrict__ tok_of,
    const int* __restrict__ mtile_e, const int* __restrict__ mtile_r0,
    const int* __restrict__ nmt,
    unsigned short* __restrict__ Hbuf)         // [CAP, F] bf16
{
  int mt = blockIdx.x;
  if (mt >= nmt[0]) return;
  int ntile = blockIdx.y;
  int e = mtile_e[mt];
  int row0 = mtile_r0[mt];

  __shared__ char lds[65536];                  // A/B double-buffered: 4 x 16KB
  int tid = threadIdx.x;
  int wid = tid >> 6, lane = tid & 63;
  int wm = (wid >> 1) * 64, wn = (wid & 1) * 64;
  int lr = lane & 15;
  int lk = (lane >> 4) * 8;

  f32x4 acc[4][4];
#pragma unroll
  for (int i = 0; i < 4; ++i)
#pragma unroll
    for (int j = 0; j < 4; ++j) acc[i][j] = (f32x4){0.f,0.f,0.f,0.f};

  const unsigned short* Wbase = W1b + ((size_t)e*FF + (size_t)ntile*BN)*HID;

  auto stage = [&](int buf, int kt) {
    int k0 = kt * BK;
#pragma unroll
    for (int it = 0; it < 4; ++it) {
      int idx = it*256 + tid;
      int r = idx >> 3;
      int c = (idx & 7) << 3;
      int tok = tok_of[row0 + r];
      gload_lds16(Xb + (size_t)tok*HID + (k0 + c), lds + buf*32768 + idx*16);
    }
#pragma unroll
    for (int it = 0; it < 4; ++it) {
      int idx = it*256 + tid;
      int r = idx >> 3;
      int c = (idx & 7) << 3;
      gload_lds16(Wbase + (size_t)r*HID + (k0 + c), lds + buf*32768 + 16384 + idx*16);
    }
  };

  auto compute = [&](int buf) {
    const char* A = lds + buf*32768;
    const char* B = lds + buf*32768 + 16384;
#pragma unroll
    for (int kk = 0; kk < 2; ++kk) {
      s16x8 af[4], bf[4];
#pragma unroll
      for (int i = 0; i < 4; ++i)
        af[i] = *(const s16x8*)(A + ((wm + i*16 + lr)*BK + kk*32 + lk)*2);
#pragma unroll
      for (int j = 0; j < 4; ++j)
        bf[j] = *(const s16x8*)(B + ((wn + j*16 + lr)*BK + kk*32 + lk)*2);
#pragma unroll
      for (int i = 0; i < 4; ++i)
#pragma unroll
        for (int j = 0; j < 4; ++j)
          acc[i][j] = __builtin_amdgcn_mfma_f32_16x16x32_bf16(af[i], bf[j], acc[i][j], 0, 0, 0);
    }
  };

  stage(0, 0);
  __syncthreads();
  int cur = 0;
  const int NK = HID / BK;                     // 16
  for (int kt = 0; kt < NK; ++kt) {
    if (kt + 1 < NK) stage(cur ^ 1, kt + 1);
    compute(cur);
    __syncthreads();
    cur ^= 1;
  }

#pragma unroll
  for (int j = 0; j < 4; ++j) {
    int col = ntile*BN + wn + j*16 + lr;
    float bb = b1[e*FF + col];
#pragma unroll
    for (int i = 0; i < 4; ++i) {
      int rbase = row0 + wm + i*16 + (lane >> 4)*4;
#pragma unroll
      for (int r = 0; r < 4; ++r) {
        float v = acc[i][j][r] + bb;
        float g = 0.5f * v * (1.f + erff(v * 0.70710678118654752f));
        Hbuf[(size_t)(rbase + r)*FF + col] = f2bf(g);
      }
    }
  }
}

// ---------------- GEMM2: Ybuf[slot][h] = (H[slot]·W2[e]^T + b2) * w ----------------
__global__ __launch_bounds__(256, 2) void gemm2_k(
    const unsigned short* __restrict__ Hbuf,   // [CAP, F] bf16
    const unsigned short* __restrict__ W2b,    // [E, H, F] bf16
    const float* __restrict__ b2,              // [E, H]
    const float* __restrict__ w_of,
    const int* __restrict__ mtile_e, const int* __restrict__ mtile_r0,
    const int* __restrict__ nmt,
    float* __restrict__ Ybuf)                  // [CAP, H] f32
{
  int mt = blockIdx.x;
  if (mt >= nmt[0]) return;
  int ntile = blockIdx.y;
  int e = mtile_e[mt];
  int row0 = mtile_r0[mt];

  __shared__ char lds[65536];
  int tid = threadIdx.x;
  int wid = tid >> 6, lane = tid & 63;
  int wm = (wid >> 1) * 64, wn = (wid & 1) * 64;
  int lr = lane & 15;
  int lk = (lane >> 4) * 8;

  f32x4 acc[4][4];
#pragma unroll
  for (int i = 0; i < 4; ++i)
#pragma unroll
    for (int j = 0; j < 4; ++j) acc[i][j] = (f32x4){0.f,0.f,0.f,0.f};

  const unsigned short* Wbase = W2b + ((size_t)e*HID + (size_t)ntile*BN)*FF;

  auto stage = [&](int buf, int kt) {
    int k0 = kt * BK;
#pragma unroll
    for (int it = 0; it < 4; ++it) {
      int idx = it*256 + tid;
      int r = idx >> 3;
      int c = (idx & 7) << 3;
      gload_lds16(Hbuf + (size_t)(row0 + r)*FF + (k0 + c), lds + buf*32768 + idx*16);
    }
#pragma unroll
    for (int it = 0; it < 4; ++it) {
      int idx = it*256 + tid;
      int r = idx >> 3;
      int c = (idx & 7) << 3;
      gload_lds16(Wbase + (size_t)r*FF + (k0 + c), lds + buf*32768 + 16384 + idx*16);
    }
  };

  auto compute = [&](int buf) {
    const char* A = lds + buf*32768;
    const char* B = lds + buf*32768 + 16384;
#pragma unroll
    for (int kk = 0; kk < 2; ++kk) {
      s16x8 af[4], bf[4];
#pragma unroll
      for (int i = 0; i < 4; ++i)
        af[i] = *(const s16x8*)(A + ((wm + i*16 + lr)*BK + kk*32 + lk)*2);
#pragma unroll
      for (int j = 0; j < 4; ++j)
        bf[j] = *(const s16x8*)(B + ((wn + j*16 + lr)*BK + kk*32 + lk)*2);
#pragma unroll
      for (int i = 0; i < 4; ++i)
#pragma unroll
        for (int j = 0; j < 4; ++j)
          acc[i][j] = __builtin_amdgcn_mfma_f32_16x16x32_bf16(af[i], bf[j], acc[i][j], 0, 0, 0);
    }
  };

  stage(0, 0);
  __syncthreads();
  int cur = 0;
  const int NK = FF / BK;                      // 64
  for (int kt = 0; kt < NK; ++kt) {
    if (kt + 1 < NK) stage(cur ^ 1, kt + 1);
    compute(cur);
    __syncthreads();
    cur ^= 1;
  }

#pragma unroll
  for (int i = 0; i < 4; ++i) {
    int rbase = row0 + wm + i*16 + (lane >> 4)*4;
    float wv[4];
#pragma unroll
    for (int r = 0; r < 4; ++r) wv[r] = w_of[rbase + r];
#pragma unroll
    for (int j = 0; j < 4; ++j) {
      int col = ntile*BN + wn + j*16 + lr;
      float bb = b2[e*HID + col];
#pragma unroll
      for (int r = 0; r < 4; ++r)
        Ybuf[(size_t)(rbase + r)*HID + col] = (acc[i][j][r] + bb) * wv[r];
    }
  }
}

// ---------------- residual + layernorm ----------------
__global__ __launch_bounds__(256) void ln_k(
    const float* __restrict__ x, const float* __restrict__ Ybuf,
    const int* __restrict__ pair_slot,
    const float* __restrict__ lnw, const float* __restrict__ lnb,
    float* __restrict__ out)
{
  int t = blockIdx.x;
  int tid = threadIdx.x;
  int s0 = pair_slot[2*t], s1 = pair_slot[2*t+1];
  float4 xv = ((const float4*)(x + (size_t)t*HID))[tid];
  float4 y0 = ((const float4*)(Ybuf + (size_t)s0*HID))[tid];
  float4 y1 = ((const float4*)(Ybuf + (size_t)s1*HID))[tid];
  float4 z;
  z.x = xv.x + y0.x + y1.x;
  z.y = xv.y + y0.y + y1.y;
  z.z = xv.z + y0.z + y1.z;
  z.w = xv.w + y0.w + y1.w;
  float s  = z.x + z.y + z.z + z.w;
  float ss = z.x*z.x + z.y*z.y + z.z*z.z + z.w*z.w;

  __shared__ float red[8];
  int lane = tid & 63, wid = tid >> 6;
#pragma unroll
  for (int o = 32; o > 0; o >>= 1) {
    s  += __shfl_down(s, o, 64);
    ss += __shfl_down(ss, o, 64);
  }
  if (lane == 0) { red[wid] = s; red[4+wid] = ss; }
  __syncthreads();
  if (tid == 0) {
    float ts  = red[0]+red[1]+red[2]+red[3];
    float tss = red[4]+red[5]+red[6]+red[7];
    float mu  = ts * (1.f/HID);
    float var = tss * (1.f/HID) - mu*mu;
    red[0] = mu; red[1] = rsqrtf(var + 1e-12f);
  }
  __syncthreads();
  float mu = red[0], inv = red[1];
  float4 wv = ((const float4*)lnw)[tid];
  float4 bv = ((const float4*)lnb)[tid];
  float4 o;
  o.x = (z.x - mu)*inv*wv.x + bv.x;
  o.y = (z.y - mu)*inv*wv.y + bv.y;
  o.z = (z.z - mu)*inv*wv.z + bv.z;
  o.w = (z.w - mu)*inv*wv.w + bv.w;
  ((float4*)(out + (size_t)t*HID))[tid] = o;
}

// ---------------- launch ----------------
extern "C" void kernel_launch(void* const* d_in, const int* in_sizes, int n_in,
                              void* d_out, int out_size, void* d_ws, size_t ws_size,
                              hipStream_t stream)
{
  const float* x   = (const float*)d_in[0];
  const float* Wr  = (const float*)d_in[1];
  const float* br  = (const float*)d_in[2];
  const float* W1  = (const float*)d_in[3];
  const float* b1  = (const float*)d_in[4];
  const float* W2  = (const float*)d_in[5];
  const float* b2  = (const float*)d_in[6];
  const float* lnw = (const float*)d_in[7];
  const float* lnb = (const float*)d_in[8];
  float* out = (float*)d_out;

  char* p = (char*)d_ws;
  auto alloc = [&](size_t b) { char* r = p; p += (b + 255) & ~(size_t)255; return r; };
  unsigned short* Xb  = (unsigned short*)alloc((size_t)T_TOK*HID*2);   // 16 MB
  unsigned short* W1b = (unsigned short*)alloc((size_t)NE*FF*HID*2);   // 64 MB
  unsigned short* W2b = (unsigned short*)alloc((size_t)NE*HID*FF*2);   // 64 MB
  unsigned short* Hb  = (unsigned short*)alloc((size_t)CAP*FF*2);      // 136 MB
  float*          Yb  = (float*)alloc((size_t)CAP*HID*4);              // 68 MB
  int*   tok_of    = (int*)alloc(CAP*4);
  float* w_of      = (float*)alloc(CAP*4);
  int*   pair_slot = (int*)alloc(T_TOK*2*4);
  int*   top_i     = (int*)alloc(T_TOK*2*4);
  float* top_w     = (float*)alloc(T_TOK*2*4);
  int*   counts    = (int*)alloc(64);          // counts[8] + fill[8]
  int*   fill      = counts + 8;
  int*   seg_start = (int*)alloc(NE*4);
  int*   mtile_e   = (int*)alloc(MT_MAX*4);
  int*   mtile_r0  = (int*)alloc(MT_MAX*4);
  int*   nmt       = (int*)alloc(4);

  hipMemsetAsync(counts, 0, 64, stream);

  cvt_k<<<4096, 256, 0, stream>>>(x,  Xb,  (long)T_TOK*HID/4);
  cvt_k<<<8192, 256, 0, stream>>>(W1, W1b, (long)NE*FF*HID/4);
  cvt_k<<<8192, 256, 0, stream>>>(W2, W2b, (long)NE*HID*FF/4);

  router_k<<<2048, 256, 0, stream>>>(x, Wr, br, top_i, top_w, counts);
  plan_k<<<1, 64, 0, stream>>>(counts, seg_start, mtile_e, mtile_r0, nmt);
  initslot_k<<<(CAP+255)/256, 256, 0, stream>>>(tok_of, w_of);
  scatter_k<<<(T_TOK+255)/256, 256, 0, stream>>>(top_i, top_w, seg_start, fill,
                                                 tok_of, w_of, pair_slot);

  gemm1_k<<<dim3(MT_MAX, FF/BN), 256, 0, stream>>>(Xb, W1b, b1, tok_of,
                                                   mtile_e, mtile_r0, nmt, Hb);
  gemm2_k<<<dim3(MT_MAX, HID/BN), 256, 0, stream>>>(Hb, W2b, b2, w_of,
                                                    mtile_e, mtile_r0, nmt, Yb);
  ln_k<<<T_TOK, 256, 0, stream>>>(x, Yb, pair_slot, lnw, lnb, out);
}